// Round 4
// baseline (7426.605 us; speedup 1.0000x reference)
//
#include <hip/hip_runtime.h>

typedef unsigned short u16;

#define DEVI static __device__ __forceinline__

DEVI float bf2f(u16 v) { return __uint_as_float(((unsigned)v) << 16); }
DEVI u16 f2bf(float f) {
  unsigned u = __float_as_uint(f);
  u += 0x7FFFu + ((u >> 16) & 1u);   // round-to-nearest-even
  return (u16)(u >> 16);
}
DEVI float4 ld4bf(const u16* p) {
  ushort4 q = *(const ushort4*)p;
  return make_float4(bf2f(q.x), bf2f(q.y), bf2f(q.z), bf2f(q.w));
}

// ---------------------------------------------------------------------------
// Shapes: N=8, C=64, CO=128, T=V=256, S=3, IC=32. All inputs/outputs FP32.
// q = flat (row<<8)+col over the last two dims; TV = 65536.
// ws (needs 128 MiB):
//   [0,   32 MiB): a_buf bf16 [8,32,65536]
//   [32,  64 MiB): b_buf bf16 [8,32,65536]
//   [0,   64 MiB): xa bf16 [8,64,65536] (overlays a/b; disjoint lifetime)
//   [64,  96 MiB): part fp32 [16,8,256,256] split-K score partials
//   [96,  98 MiB): tot fp32 [8,256,256]
//   [98, 100 MiB): adapt fp32 [8,256,256]
//   [0,  128 MiB): gcn bf16 [8,128,65536] (after subset loop only)
// y accumulator = d_out as fp32 [8,128,65536]; dead before k_out final write.
// ---------------------------------------------------------------------------

__global__ void k_diag(float* out, float v) { out[0] = v; }

// a/b 1x1 convs -> bf16. Block: 64 rows (32 a + 32 b) x 64 px, K=64.
__global__ __launch_bounds__(256) void k_ab(
    const float* __restrict__ x, const float* __restrict__ wa, const float* __restrict__ ba,
    const float* __restrict__ wb, const float* __restrict__ bb,
    u16* __restrict__ a_buf, u16* __restrict__ b_buf, int sub)
{
  __shared__ __align__(16) float Ws[64 * 64]; // [c][r]
  __shared__ __align__(16) float Xs[64 * 64]; // [c][px]
  const int n = blockIdx.y;
  const int p0 = blockIdx.x << 6;
  const int tid = threadIdx.x;

  #pragma unroll
  for (int j = 0; j < 16; ++j) {
    int e = tid + j * 256;
    int c = e >> 6, r = e & 63;
    float wv = (r < 32) ? wa[sub * 2048 + r * 64 + c]
                        : wb[sub * 2048 + (r - 32) * 64 + c];
    Ws[c * 64 + r] = wv;
  }
  #pragma unroll
  for (int j = 0; j < 4; ++j) {
    int e = (tid + j * 256) * 4;
    int c = e >> 6, px = e & 63;
    *(float4*)&Xs[c * 64 + px] = *(const float4*)(x + (((size_t)(n << 6) + c) << 16) + p0 + px);
  }
  __syncthreads();
  const int rb = (tid & 15) << 2;
  const int pb = (tid >> 4) << 2;
  float acc[4][4] = {};
  #pragma unroll 4
  for (int c = 0; c < 64; ++c) {
    float4 wv = *(const float4*)&Ws[c * 64 + rb];
    float4 xv = *(const float4*)&Xs[c * 64 + pb];
    float w[4] = {wv.x, wv.y, wv.z, wv.w};
    float xr[4] = {xv.x, xv.y, xv.z, xv.w};
    #pragma unroll
    for (int a = 0; a < 4; ++a)
      #pragma unroll
      for (int b = 0; b < 4; ++b) acc[a][b] += w[a] * xr[b];
  }
  #pragma unroll
  for (int a = 0; a < 4; ++a) {
    int r = rb + a;
    float bias; u16* dst;
    if (r < 32) { bias = ba[sub * 32 + r]; dst = a_buf + (((n * 32 + r) << 16) + p0 + pb); }
    else        { bias = bb[sub * 32 + r - 32]; dst = b_buf + (((n * 32 + r - 32) << 16) + p0 + pb); }
    ushort4 st;
    st.x = f2bf(acc[a][0] + bias); st.y = f2bf(acc[a][1] + bias);
    st.z = f2bf(acc[a][2] + bias); st.w = f2bf(acc[a][3] + bias);
    *(ushort4*)dst = st;
  }
}

// scores partials, split-K=16 over v: part[p,n,t,s] = sum_{c, v in [16p,16p+16)} a*b
__global__ __launch_bounds__(256) void k_sc(
    const u16* __restrict__ a_buf, const u16* __restrict__ b_buf,
    float* __restrict__ part)
{
  __shared__ __align__(16) float As[16 * 128]; // [k(v)][t]
  __shared__ __align__(16) float Bs[16 * 128]; // [k(v)][s]
  const int n = blockIdx.z;
  const int p = blockIdx.y;
  const int t0 = (blockIdx.x >> 1) << 7;
  const int s0 = (blockIdx.x & 1) << 7;
  const int v0 = p << 4;
  const int tid = threadIdx.x;
  const int wave = tid >> 6, lane = tid & 63;
  const int r0 = ((wave & 1) << 6) + ((lane >> 3) << 3);  // t within tile
  const int c0 = ((wave >> 1) << 6) + ((lane & 7) << 3);  // s within tile
  const int tt = tid >> 1, hf = (tid & 1) << 3;
  float acc[8][8] = {};
  for (int c = 0; c < 32; ++c) {
    const u16* ap = a_buf + ((n * 32 + c) << 16);
    const u16* bp = b_buf + ((n * 32 + c) << 16);
    __syncthreads();
    {
      ushort4 qa0 = *(const ushort4*)(ap + (t0 + tt) * 256 + v0 + hf);
      ushort4 qa1 = *(const ushort4*)(ap + (t0 + tt) * 256 + v0 + hf + 4);
      As[(hf + 0) * 128 + tt] = bf2f(qa0.x); As[(hf + 1) * 128 + tt] = bf2f(qa0.y);
      As[(hf + 2) * 128 + tt] = bf2f(qa0.z); As[(hf + 3) * 128 + tt] = bf2f(qa0.w);
      As[(hf + 4) * 128 + tt] = bf2f(qa1.x); As[(hf + 5) * 128 + tt] = bf2f(qa1.y);
      As[(hf + 6) * 128 + tt] = bf2f(qa1.z); As[(hf + 7) * 128 + tt] = bf2f(qa1.w);
      ushort4 qb0 = *(const ushort4*)(bp + (s0 + tt) * 256 + v0 + hf);
      ushort4 qb1 = *(const ushort4*)(bp + (s0 + tt) * 256 + v0 + hf + 4);
      Bs[(hf + 0) * 128 + tt] = bf2f(qb0.x); Bs[(hf + 1) * 128 + tt] = bf2f(qb0.y);
      Bs[(hf + 2) * 128 + tt] = bf2f(qb0.z); Bs[(hf + 3) * 128 + tt] = bf2f(qb0.w);
      Bs[(hf + 4) * 128 + tt] = bf2f(qb1.x); Bs[(hf + 5) * 128 + tt] = bf2f(qb1.y);
      Bs[(hf + 6) * 128 + tt] = bf2f(qb1.z); Bs[(hf + 7) * 128 + tt] = bf2f(qb1.w);
    }
    __syncthreads();
    #pragma unroll
    for (int kk = 0; kk < 16; ++kk) {
      float av[8], bv[8];
      *(float4*)&av[0] = *(const float4*)&As[kk * 128 + r0];
      *(float4*)&av[4] = *(const float4*)&As[kk * 128 + r0 + 4];
      *(float4*)&bv[0] = *(const float4*)&Bs[kk * 128 + c0];
      *(float4*)&bv[4] = *(const float4*)&Bs[kk * 128 + c0 + 4];
      #pragma unroll
      for (int a = 0; a < 8; ++a)
        #pragma unroll
        for (int b = 0; b < 8; ++b) acc[a][b] += av[a] * bv[b];
    }
  }
  float* pp = part + (((p << 3) + n) << 16);
  #pragma unroll
  for (int a = 0; a < 8; ++a) {
    float* dst = pp + (t0 + r0 + a) * 256 + s0 + c0;
    *(float4*)dst = make_float4(acc[a][0], acc[a][1], acc[a][2], acc[a][3]);
    *(float4*)(dst + 4) = make_float4(acc[a][4], acc[a][5], acc[a][6], acc[a][7]);
  }
}

// softmax over t (axis=-2) per (n,s) + adapt = mat_adj + adj_w + att.
__global__ __launch_bounds__(256) void k_soft(
    const float* __restrict__ part, const float* __restrict__ madj,
    const float* __restrict__ wadj, float* __restrict__ tot,
    float* __restrict__ adapt, int sub)
{
  const int n = blockIdx.x;
  const int s = threadIdx.x;
  const float invV = 1.0f / 256.0f;
  float* tp = tot + (n << 16);
  const float* p0 = part + (n << 16);
  float m = -1e30f;
  for (int t = 0; t < 256; ++t) {
    int off = t * 256 + s;
    float v = 0.f;
    #pragma unroll
    for (int j = 0; j < 16; ++j) v += p0[j * 524288 + off];
    v *= invV;
    tp[off] = v;
    m = fmaxf(m, v);
  }
  float sum = 0.f;
  for (int t = 0; t < 256; ++t) sum += __expf(tp[t * 256 + s] - m);
  float inv = 1.0f / sum;
  const float* ma = madj + (sub << 16);
  const float* wa2 = wadj + (sub << 16);
  float* adp = adapt + (n << 16);
  for (int t = 0; t < 256; ++t) {
    int off = t * 256 + s;
    float e = __expf(tp[off] - m) * inv;
    adp[off] = e + ma[off] + wa2[off];
  }
}

// xa[n,c,v,s] = sum_t x[n,c,t,v] * adapt[n,t,s] -> bf16; per (n,c) 256^3 gemm.
__global__ __launch_bounds__(256) void k_xa(
    const float* __restrict__ x, const float* __restrict__ adapt,
    u16* __restrict__ xa)
{
  __shared__ __align__(16) float As[32 * 128]; // [k(t)][v]
  __shared__ __align__(16) float Bs[32 * 128]; // [k(t)][s]
  const int n = blockIdx.z, c = blockIdx.y;
  const int v0 = (blockIdx.x >> 1) << 7;
  const int s0 = (blockIdx.x & 1) << 7;
  const int tid = threadIdx.x;
  const int wave = tid >> 6, lane = tid & 63;
  const int r0 = ((wave & 1) << 6) + ((lane >> 3) << 3);  // v within tile
  const int c0 = ((wave >> 1) << 6) + ((lane & 7) << 3);  // s within tile
  const float* xp = x + (((size_t)(n << 6) + c) << 16);
  const float* ap = adapt + (n << 16);
  float acc[8][8] = {};
  for (int tc = 0; tc < 8; ++tc) {
    const int t0 = tc << 5;
    __syncthreads();
    #pragma unroll
    for (int j = 0; j < 4; ++j) {
      int e = (tid + j * 256) * 4;
      int col = e & 127, kk = e >> 7;
      *(float4*)&As[kk * 128 + col] = *(const float4*)(xp + ((t0 + kk) << 8) + v0 + col);
      *(float4*)&Bs[kk * 128 + col] = *(const float4*)(ap + ((t0 + kk) << 8) + s0 + col);
    }
    __syncthreads();
    #pragma unroll
    for (int kk = 0; kk < 32; ++kk) {
      float av[8], bv[8];
      *(float4*)&av[0] = *(const float4*)&As[kk * 128 + r0];
      *(float4*)&av[4] = *(const float4*)&As[kk * 128 + r0 + 4];
      *(float4*)&bv[0] = *(const float4*)&Bs[kk * 128 + c0];
      *(float4*)&bv[4] = *(const float4*)&Bs[kk * 128 + c0 + 4];
      #pragma unroll
      for (int a = 0; a < 8; ++a)
        #pragma unroll
        for (int b = 0; b < 8; ++b) acc[a][b] += av[a] * bv[b];
    }
  }
  u16* xo = xa + (((n << 6) + c) << 16);
  #pragma unroll
  for (int a = 0; a < 8; ++a) {
    u16* dst = xo + (v0 + r0 + a) * 256 + s0 + c0;
    ushort4 u0, u1;
    u0.x = f2bf(acc[a][0]); u0.y = f2bf(acc[a][1]);
    u0.z = f2bf(acc[a][2]); u0.w = f2bf(acc[a][3]);
    u1.x = f2bf(acc[a][4]); u1.y = f2bf(acc[a][5]);
    u1.z = f2bf(acc[a][6]); u1.w = f2bf(acc[a][7]);
    *(ushort4*)dst = u0;
    *(ushort4*)(dst + 4) = u1;
  }
}

// y[n,o,q] (+)= sum_c wd[i,o,c]*xa[n,c,q] + bd[i,o]; y fp32 in d_out.
__global__ __launch_bounds__(256) void k_wd(
    const u16* __restrict__ xa, const float* __restrict__ wd,
    const float* __restrict__ bd, float* __restrict__ y, int sub, int init)
{
  __shared__ __align__(16) float Ws[32 * 128]; // [c][o]
  __shared__ __align__(16) float Xs[32 * 128]; // [c][q]
  const int n = blockIdx.y;
  const int q0 = blockIdx.x << 7;
  const int tid = threadIdx.x;
  const int wave = tid >> 6, lane = tid & 63;
  const int o0 = ((wave & 1) << 6) + ((lane >> 3) << 3);
  const int qq = ((wave >> 1) << 6) + ((lane & 7) << 3);
  float acc[8][8] = {};
  for (int kc = 0; kc < 2; ++kc) {
    const int cb = kc << 5;
    __syncthreads();
    #pragma unroll
    for (int j = 0; j < 16; ++j) {
      int e = tid + j * 256;
      int c = e >> 7, o = e & 127;
      Ws[e] = wd[sub * 8192 + o * 64 + cb + c];
    }
    #pragma unroll
    for (int j = 0; j < 4; ++j) {
      int e = (tid + j * 256) * 4;
      int c = e >> 7, q = e & 127;
      *(float4*)&Xs[e] = ld4bf(xa + (((n << 6) + cb + c) << 16) + q0 + q);
    }
    __syncthreads();
    #pragma unroll
    for (int kk = 0; kk < 32; ++kk) {
      float ov[8], qv[8];
      *(float4*)&ov[0] = *(const float4*)&Ws[kk * 128 + o0];
      *(float4*)&ov[4] = *(const float4*)&Ws[kk * 128 + o0 + 4];
      *(float4*)&qv[0] = *(const float4*)&Xs[kk * 128 + qq];
      *(float4*)&qv[4] = *(const float4*)&Xs[kk * 128 + qq + 4];
      #pragma unroll
      for (int a = 0; a < 8; ++a)
        #pragma unroll
        for (int b = 0; b < 8; ++b) acc[a][b] += ov[a] * qv[b];
    }
  }
  #pragma unroll
  for (int a = 0; a < 8; ++a) {
    int o = o0 + a;
    float bias = bd[sub * 128 + o];
    float* dst = y + (((size_t)(n << 7) + o) << 16) + q0 + qq;
    float4 r0 = make_float4(acc[a][0] + bias, acc[a][1] + bias, acc[a][2] + bias, acc[a][3] + bias);
    float4 r1 = make_float4(acc[a][4] + bias, acc[a][5] + bias, acc[a][6] + bias, acc[a][7] + bias);
    if (!init) {
      float4 y0 = *(const float4*)dst, y1 = *(const float4*)(dst + 4);
      r0.x += y0.x; r0.y += y0.y; r0.z += y0.z; r0.w += y0.w;
      r1.x += y1.x; r1.y += y1.y; r1.z += y1.z; r1.w += y1.w;
    }
    *(float4*)dst = r0;
    *(float4*)(dst + 4) = r1;
  }
}

// gcn[n,o,q] = relu(bn_g(y) + bn_c(conv1x1(x,cres)+cres_b)) -> bf16 (ws)
__global__ __launch_bounds__(256) void k_gcn(
    const float* __restrict__ x, const float* __restrict__ cw,
    const float* __restrict__ cb, const float* __restrict__ cbn,
    const float* __restrict__ gbn, const float* __restrict__ y,
    u16* __restrict__ gcn)
{
  __shared__ __align__(16) float Ws[32 * 128];
  __shared__ __align__(16) float Xs[32 * 128];
  const int n = blockIdx.y;
  const int q0 = blockIdx.x << 7;
  const int tid = threadIdx.x;
  const int wave = tid >> 6, lane = tid & 63;
  const int o0 = ((wave & 1) << 6) + ((lane >> 3) << 3);
  const int qq = ((wave >> 1) << 6) + ((lane & 7) << 3);
  float acc[8][8] = {};
  for (int kc = 0; kc < 2; ++kc) {
    const int cbase = kc << 5;
    __syncthreads();
    #pragma unroll
    for (int j = 0; j < 16; ++j) {
      int e = tid + j * 256;
      int c = e >> 7, o = e & 127;
      Ws[e] = cw[o * 64 + cbase + c];
    }
    #pragma unroll
    for (int j = 0; j < 4; ++j) {
      int e = (tid + j * 256) * 4;
      int c = e >> 7, q = e & 127;
      *(float4*)&Xs[e] = *(const float4*)(x + (((size_t)(n << 6) + cbase + c) << 16) + q0 + q);
    }
    __syncthreads();
    #pragma unroll
    for (int kk = 0; kk < 32; ++kk) {
      float ov[8], qv[8];
      *(float4*)&ov[0] = *(const float4*)&Ws[kk * 128 + o0];
      *(float4*)&ov[4] = *(const float4*)&Ws[kk * 128 + o0 + 4];
      *(float4*)&qv[0] = *(const float4*)&Xs[kk * 128 + qq];
      *(float4*)&qv[4] = *(const float4*)&Xs[kk * 128 + qq + 4];
      #pragma unroll
      for (int a = 0; a < 8; ++a)
        #pragma unroll
        for (int b = 0; b < 8; ++b) acc[a][b] += ov[a] * qv[b];
    }
  }
  #pragma unroll
  for (int a = 0; a < 8; ++a) {
    int o = o0 + a;
    float sc = cbn[o] * rsqrtf(cbn[384 + o] + 1e-5f);
    float sg = gbn[o] * rsqrtf(gbn[384 + o] + 1e-5f);
    float kk2 = (cb[o] - cbn[256 + o]) * sc + cbn[128 + o]
              - gbn[256 + o] * sg + gbn[128 + o];
    const float* yp = y + (((size_t)(n << 7) + o) << 16) + q0 + qq;
    u16* dst = gcn + (((n << 7) + o) << 16) + q0 + qq;
    float4 ya = *(const float4*)yp, yb = *(const float4*)(yp + 4);
    float vy[8] = {ya.x, ya.y, ya.z, ya.w, yb.x, yb.y, yb.z, yb.w};
    ushort4 u0, u1;
    u0.x = f2bf(fmaxf(sg * vy[0] + sc * acc[a][0] + kk2, 0.f));
    u0.y = f2bf(fmaxf(sg * vy[1] + sc * acc[a][1] + kk2, 0.f));
    u0.z = f2bf(fmaxf(sg * vy[2] + sc * acc[a][2] + kk2, 0.f));
    u0.w = f2bf(fmaxf(sg * vy[3] + sc * acc[a][3] + kk2, 0.f));
    u1.x = f2bf(fmaxf(sg * vy[4] + sc * acc[a][4] + kk2, 0.f));
    u1.y = f2bf(fmaxf(sg * vy[5] + sc * acc[a][5] + kk2, 0.f));
    u1.z = f2bf(fmaxf(sg * vy[6] + sc * acc[a][6] + kk2, 0.f));
    u1.w = f2bf(fmaxf(sg * vy[7] + sc * acc[a][7] + kk2, 0.f));
    *(ushort4*)dst = u0;
    *(ushort4*)(dst + 4) = u1;
  }
}

// out = relu(bn_t(tcn9(gcn)+tb) + bn_r(conv1x1(x,rt)+rb)) -> fp32 (d_out)
// Single GEMM, K = 1152 (tcn, pre-scaled by bn_t) + 64 (rt, pre-scaled by bn_r).
__global__ __launch_bounds__(256) void k_out(
    const u16* __restrict__ gcn, const float* __restrict__ x,
    const float* __restrict__ tw, const float* __restrict__ tb, const float* __restrict__ tbn,
    const float* __restrict__ rw, const float* __restrict__ rb, const float* __restrict__ rbn,
    float* __restrict__ out)
{
  __shared__ __align__(16) float Wc[32 * 128];
  __shared__ __align__(16) float Gc[32 * 128];
  __shared__ float s_st[128], s_sr[128], s_kk[128];
  const int n = blockIdx.y;
  const int q0 = blockIdx.x << 7;
  const int h = q0 >> 8;
  const int w0 = q0 & 255;
  const int tid = threadIdx.x;
  if (tid < 128) {
    int o = tid;
    float st = tbn[o] * rsqrtf(tbn[384 + o] + 1e-5f);
    float sr = rbn[o] * rsqrtf(rbn[384 + o] + 1e-5f);
    s_st[o] = st; s_sr[o] = sr;
    s_kk[o] = (tb[o] - tbn[256 + o]) * st + tbn[128 + o]
            + (rb[o] - rbn[256 + o]) * sr + rbn[128 + o];
  }
  __syncthreads();
  const int wave = tid >> 6, lane = tid & 63;
  const int o0 = ((wave & 1) << 6) + ((lane >> 3) << 3);
  const int qq = ((wave >> 1) << 6) + ((lane & 7) << 3);
  float acc[8][8] = {};
  for (int kc = 0; kc < 38; ++kc) {
    __syncthreads();
    #pragma unroll
    for (int j = 0; j < 16; ++j) {
      int e = tid + j * 256;
      int kk = e >> 7, o = e & 127;
      int kidx = kc * 32 + kk;
      float wv;
      if (kidx < 1152) wv = s_st[o] * tw[o * 1152 + kidx];
      else             wv = s_sr[o] * rw[o * 64 + (kidx - 1152)];
      Wc[kk * 128 + o] = wv;
    }
    #pragma unroll
    for (int j = 0; j < 4; ++j) {
      int e = (tid + j * 256) * 4;
      int kk = e >> 7, q2 = e & 127;
      int kidx = kc * 32 + kk;
      float4 gv;
      if (kidx < 1152) {
        int i = kidx / 9, kh = kidx - i * 9;
        int h2 = h + kh - 4;
        if ((unsigned)h2 < 256u)
          gv = ld4bf(gcn + (((n << 7) + i) << 16) + (h2 << 8) + w0 + q2);
        else gv = make_float4(0.f, 0.f, 0.f, 0.f);
      } else {
        int cc = kidx - 1152;
        gv = *(const float4*)(x + (((size_t)(n << 6) + cc) << 16) + q0 + q2);
      }
      *(float4*)&Gc[kk * 128 + q2] = gv;
    }
    __syncthreads();
    #pragma unroll
    for (int kk = 0; kk < 32; ++kk) {
      float ov[8], qv[8];
      *(float4*)&ov[0] = *(const float4*)&Wc[kk * 128 + o0];
      *(float4*)&ov[4] = *(const float4*)&Wc[kk * 128 + o0 + 4];
      *(float4*)&qv[0] = *(const float4*)&Gc[kk * 128 + qq];
      *(float4*)&qv[4] = *(const float4*)&Gc[kk * 128 + qq + 4];
      #pragma unroll
      for (int a = 0; a < 8; ++a)
        #pragma unroll
        for (int b = 0; b < 8; ++b) acc[a][b] += ov[a] * qv[b];
    }
  }
  #pragma unroll
  for (int a = 0; a < 8; ++a) {
    int o = o0 + a;
    float kadd = s_kk[o];
    float* dst = out + (((size_t)(n << 7) + o) << 16) + q0 + qq;
    float4 r0 = make_float4(fmaxf(acc[a][0] + kadd, 0.f), fmaxf(acc[a][1] + kadd, 0.f),
                            fmaxf(acc[a][2] + kadd, 0.f), fmaxf(acc[a][3] + kadd, 0.f));
    float4 r1 = make_float4(fmaxf(acc[a][4] + kadd, 0.f), fmaxf(acc[a][5] + kadd, 0.f),
                            fmaxf(acc[a][6] + kadd, 0.f), fmaxf(acc[a][7] + kadd, 0.f));
    *(float4*)dst = r0;
    *(float4*)(dst + 4) = r1;
  }
}

extern "C" void kernel_launch(void* const* d_in, const int* in_sizes, int n_in,
                              void* d_out, int out_size, void* d_ws, size_t ws_size,
                              hipStream_t stream) {
  const float* x       = (const float*)d_in[0];
  const float* mat_adj = (const float*)d_in[1];
  const float* adj_w   = (const float*)d_in[2];
  const float* wa      = (const float*)d_in[3];
  const float* ba      = (const float*)d_in[4];
  const float* wb      = (const float*)d_in[5];
  const float* bb      = (const float*)d_in[6];
  const float* wd      = (const float*)d_in[7];
  const float* bd      = (const float*)d_in[8];
  const float* gcn_bn  = (const float*)d_in[9];
  const float* cres_w  = (const float*)d_in[10];
  const float* cres_b  = (const float*)d_in[11];
  const float* cres_bn = (const float*)d_in[12];
  const float* tcn_w   = (const float*)d_in[13];
  const float* tcn_b   = (const float*)d_in[14];
  const float* tcn_bn  = (const float*)d_in[15];
  const float* rt_w    = (const float*)d_in[16];
  const float* rt_b    = (const float*)d_in[17];
  const float* rt_bn   = (const float*)d_in[18];
  float* out = (float*)d_out;

  (void)hipGetLastError();  // clear any stale error

  // Execution sentinel: if no kernel below runs, out[0] = 0x42424242 ≈ 48.57.
  hipMemsetAsync(d_out, 0x42, 4, stream);

  // Contract sanity: wrong input order/shape -> loud diag code.
  if (n_in != 19)                    { k_diag<<<1,1,0,stream>>>(out, 2019.f); return; }
  if (in_sizes[0]  != 33554432)      { k_diag<<<1,1,0,stream>>>(out, 2000.f); return; }
  if (in_sizes[3]  != 6144)          { k_diag<<<1,1,0,stream>>>(out, 2003.f); return; }
  if (in_sizes[7]  != 24576)         { k_diag<<<1,1,0,stream>>>(out, 2007.f); return; }
  if (in_sizes[9]  != 512)           { k_diag<<<1,1,0,stream>>>(out, 2009.f); return; }
  if (in_sizes[13] != 147456)        { k_diag<<<1,1,0,stream>>>(out, 2013.f); return; }
  if (in_sizes[16] != 8192)          { k_diag<<<1,1,0,stream>>>(out, 2016.f); return; }
  if (out_size != 67108864)          { k_diag<<<1,1,0,stream>>>(out, 3000.f); return; }
  if (ws_size < 134217728ull)        { k_diag<<<1,1,0,stream>>>(out, (float)ws_size); return; }

  float* wsf   = (float*)d_ws;
  u16*   a_buf = (u16*)d_ws;                 // [0, 32 MiB)
  u16*   b_buf = a_buf + 16777216;           // [32, 64 MiB)
  u16*   xa    = (u16*)d_ws;                 // overlays a+b, [0, 64 MiB)
  float* part  = wsf + 16777216;             // [64, 96 MiB)
  float* tot   = wsf + 25165824;             // [96, 98 MiB)
  float* adapt = wsf + 25690112;             // [98, 100 MiB)
  u16*   gcn   = (u16*)d_ws;                 // [0, 128 MiB) after subsets
  float* y     = (float*)d_out;              // fp32 accumulator in d_out

  for (int i = 0; i < 3; ++i) {
    k_ab  <<<dim3(1024, 8),  256, 0, stream>>>(x, wa, ba, wb, bb, a_buf, b_buf, i);
    k_sc  <<<dim3(4, 16, 8), 256, 0, stream>>>(a_buf, b_buf, part);
    k_soft<<<dim3(8),        256, 0, stream>>>(part, mat_adj, adj_w, tot, adapt, i);
    k_xa  <<<dim3(4, 64, 8), 256, 0, stream>>>(x, adapt, xa);
    k_wd  <<<dim3(512, 8),   256, 0, stream>>>(xa, wd, bd, y, i, i == 0);
  }
  k_gcn<<<dim3(512, 8), 256, 0, stream>>>(x, cres_w, cres_b, cres_bn, gcn_bn, y, gcn);
  k_out<<<dim3(512, 8), 256, 0, stream>>>(gcn, x, tcn_w, tcn_b, tcn_bn,
                                          rt_w, rt_b, rt_bn, out);

  // Surface any silent launch failure via the absmax channel.
  hipError_t le = hipGetLastError();
  if (le != hipSuccess) {
    k_diag<<<1, 1, 0, stream>>>(out, 1.0e9f + (float)(int)le);
  }
}